// Round 5
// baseline (175.483 us; speedup 1.0000x reference)
//
#include <hip/hip_runtime.h>
#include <math.h>

#define NW 14
#define NSTATE 16384           // 2^14 amplitudes
#define NL 4
#define BATCH 128
#define TPB 1024

// ---------------------------------------------------------------------------
// Index convention (round-1 PASSING kernel): wire i lives at bit (13-i).
//
// CNOT-ring composite: psi_new[idx] = psi_old[R(idx)],
//   R: y_p = x_p ^ x_{p+1} (p=0..11), y_12 = x12^x13^x0, y_13 = x13^x0.
// Scatter form: value at I goes to R^{-1}(I). GF(2)-linear basis images
// (each verified by applying R): R^{-1}(e_j) = ((2<<j)-1) | (1<<13) (j<=11),
// R^{-1}(e_12) = 0x3FFF, R^{-1}(e_13) = 0x1FFF.
// ---------------------------------------------------------------------------

#define B4_  0x201Fu
#define B5_  0x203Fu
#define B12_ 0x3FFFu
#define B13_ 0x1FFFu

// Apply SU(2) gate [[a,b],[-b*,a*]] (g={ar,ai,br,bi}) on register pairs
// (k, k|M). Register k holds the amplitude whose index-bit equals
// (swizzle s)-bit for that position, so when the s-bit is set the pair
// orientation is swapped: apply X*G*X = [[a*,-b*],[b,a]] instead, which in
// this packing is just (ai,br) -> (-ai,-br).
template<int M>
__device__ __forceinline__ void gate16(float2* r, float4 g, unsigned s) {
    const float f = (s & (unsigned)M) ? -1.0f : 1.0f;
    g.y *= f;   // ai
    g.z *= f;   // br
#pragma unroll
    for (int k = 0; k < 16; ++k) {
        if ((k & M) == 0) {
            const float x0 = r[k].x,   y0 = r[k].y;
            const float x1 = r[k|M].x, y1 = r[k|M].y;
            r[k].x   =  g.x*x0 - g.y*y0 + g.z*x1 - g.w*y1;
            r[k].y   =  g.x*y0 + g.y*x0 + g.z*y1 + g.w*x1;
            r[k|M].x = -g.z*x0 - g.w*y0 + g.x*x1 + g.y*y1;
            r[k|M].y = -g.z*y0 + g.w*x0 + g.x*y1 - g.y*x1;
        }
    }
}

// One pass: gather 16 amps varying in index bits [J0, J0+3], apply those 4
// gates in registers, scatter back. XOR swizzle (k^s) spreads bank pairs
// (4-way max aliasing instead of 32-way); orientation handled in gate16.
template<int J0>
__device__ __forceinline__ void pass4gates(float2* psi, const float4* gc4,
                                           int l, unsigned t) {
    const unsigned s = t & 15u;
    const unsigned low  = t & ((1u << J0) - 1u);
    const unsigned high = (t >> J0) << (J0 + 4);
    float2 r[16];
#pragma unroll
    for (int k = 0; k < 16; ++k)
        r[k] = psi[low | ((unsigned)(k ^ (int)s) << J0) | high];
    gate16<1>(r, gc4[l*NW + (13 - (J0+0))], s);
    gate16<2>(r, gc4[l*NW + (13 - (J0+1))], s);
    gate16<4>(r, gc4[l*NW + (13 - (J0+2))], s);
    gate16<8>(r, gc4[l*NW + (13 - (J0+3))], s);
#pragma unroll
    for (int k = 0; k < 16; ++k)
        psi[low | ((unsigned)(k ^ (int)s) << J0) | high] = r[k];
}

// Last pass of a layer: gates on bits 12,13 (wires 1,0) + CNOT-ring
// permutation folded into the scatter. Thread owns index bits {0..3}<-t&15,
// {4,5}<-u&3, {6..11}<-t>>4, {12,13}<-u>>2 where u=k^s.
__device__ __forceinline__ void pass_last(float2* psi, const float4* gc4,
                                          int l, unsigned t) {
    const unsigned s = t & 15u;
    const unsigned base = (t & 15u) | ((t >> 4) << 6);
    float2 r[16];
#pragma unroll
    for (int k = 0; k < 16; ++k) {
        const unsigned u = (unsigned)(k ^ (int)s) & 15u;
        r[k] = psi[base | ((u & 3u) << 4) | ((u >> 2) << 12)];
    }
    gate16<4>(r, gc4[l*NW + 1], s);   // index bit 12 -> wire 1
    gate16<8>(r, gc4[l*NW + 0], s);   // index bit 13 -> wire 0
    __syncthreads();               // in-place permutation: drain all gathers
    // R^{-1}(base) via suffix-XOR (base has bits only in 0..11):
    // low-12 = suffix-xor, bit13 = popcount parity, bit12 = 0.
    unsigned v = base;
    v ^= v >> 1; v ^= v >> 2; v ^= v >> 4; v ^= v >> 8;
    const unsigned Rbase = (v & 0x0FFFu) | ((v & 1u) << 13);
    const unsigned Rs = ((s & 1u) ? B4_  : 0u) ^ ((s & 2u) ? B5_  : 0u) ^
                        ((s & 4u) ? B12_ : 0u) ^ ((s & 8u) ? B13_ : 0u);
    const unsigned Rb = Rbase ^ Rs;
#pragma unroll
    for (int k = 0; k < 16; ++k) {
        const unsigned CK = ((k & 1) ? B4_  : 0u) ^ ((k & 2) ? B5_  : 0u) ^
                            ((k & 4) ? B12_ : 0u) ^ ((k & 8) ? B13_ : 0u);
        psi[Rb ^ CK] = r[k];
    }
}

// amdgpu_waves_per_eu(4,4): the 128 KB dynamic LDS pins real occupancy at
// 1 block/CU = 4 waves/EU, but the compiler can't see dynamic LDS and
// targets 8 waves/EU -> 64-VGPR cap -> spills r[16] to scratch (observed:
// 114 MB HBM/dispatch, VGPR_Count=64 in rounds 3-4; launch_bounds' 2nd arg
// is only a MIN and didn't move it). Pinning max=4 raises the cap to 128
// VGPRs so the 32-VGPR r[16] working set stays in registers.
__global__ __launch_bounds__(TPB)
__attribute__((amdgpu_waves_per_eu(4, 4)))
void qsim_kernel(
    const float* __restrict__ states,
    const float* __restrict__ weights,
    const float* __restrict__ head_w,
    const float* __restrict__ head_b,
    float* __restrict__ out)
{
    extern __shared__ float2 psi[];        // 16384 float2 = 128 KB
    __shared__ float4 gc4[NL * NW];        // fused gate coefs (a, b)
    __shared__ float wsum[TPB / 64];

    const int b = blockIdx.x;
    const unsigned tid = threadIdx.x;

    // One-time gate-coef precompute: G = RZ(t2)*RX(t1), layer 0 folds the
    // data-encoding RX(|x_w|) in (RX angles add). SU(2): a=g00, b=g01.
    if (tid < NL * NW) {
        const int l = (int)tid / NW, w = (int)tid % NW;
        float t1 = weights[tid * 2 + 0];
        float t2 = weights[tid * 2 + 1];
        if (l == 0) t1 += fabsf(states[(size_t)b * NSTATE + w]);
        float s, c, sz, cz;
        sincosf(0.5f * t1, &s, &c);
        sincosf(0.5f * t2, &sz, &cz);
        gc4[tid] = make_float4(c * cz, -c * sz, -s * sz, -s * cz);
    }
    // |0...0>
    for (unsigned i = tid; i < NSTATE; i += TPB)
        psi[i] = make_float2(i == 0 ? 1.0f : 0.0f, 0.0f);
    __syncthreads();

    for (int l = 0; l < NL; ++l) {
        pass4gates<0>(psi, gc4, l, tid);  __syncthreads();  // wires 13..10
        pass4gates<4>(psi, gc4, l, tid);  __syncthreads();  // wires 9..6
        pass4gates<8>(psi, gc4, l, tid);  __syncthreads();  // wires 5..2
        pass_last    (psi, gc4, l, tid);  __syncthreads();  // wires 1,0 + ring
    }

    // out[b] = sum |amp|^2 * cv(idx) + head_b ; cv = sum_i hw[i]*(1-2*bit)
    float hw[NW];
#pragma unroll
    for (int i = 0; i < NW; ++i) hw[i] = head_w[i];

    const unsigned s = tid & 15u;
    // cvbase for index bits 4..13 (= bits 0..9 of tid); bit j <-> wire 13-j
    float cvbase = 0.0f;
#pragma unroll
    for (int i = 0; i < NW; ++i) cvbase += hw[i];
#pragma unroll
    for (int j = 4; j < 14; ++j)
        if ((tid >> (j - 4)) & 1u) cvbase -= 2.0f * hw[13 - j];

    float acc = 0.0f;
#pragma unroll
    for (int k = 0; k < 16; ++k) {
        const unsigned u = (unsigned)(k ^ (int)s) & 15u;   // index bits 0..3
        const float2 a = psi[u | (tid << 4)];
        const float p = a.x * a.x + a.y * a.y;
        float cv = cvbase;
        if (u & 1u) cv -= 2.0f * hw[13];
        if (u & 2u) cv -= 2.0f * hw[12];
        if (u & 4u) cv -= 2.0f * hw[11];
        if (u & 8u) cv -= 2.0f * hw[10];
        acc += p * cv;
    }
#pragma unroll
    for (int off = 32; off > 0; off >>= 1)
        acc += __shfl_down(acc, off, 64);
    if ((tid & 63u) == 0) wsum[tid >> 6] = acc;
    __syncthreads();
    if (tid == 0) {
        float tot = 0.0f;
#pragma unroll
        for (int i = 0; i < TPB / 64; ++i) tot += wsum[i];
        out[b] = tot + head_b[0];
    }
}

extern "C" void kernel_launch(void* const* d_in, const int* in_sizes, int n_in,
                              void* d_out, int out_size, void* d_ws, size_t ws_size,
                              hipStream_t stream) {
    const float* states  = (const float*)d_in[0];  // (128, 16384)
    const float* weights = (const float*)d_in[1];  // (4, 14, 2)
    const float* head_w  = (const float*)d_in[2];  // (1, 14)
    const float* head_b  = (const float*)d_in[3];  // (1,)
    float* out = (float*)d_out;                    // (128,)
    qsim_kernel<<<BATCH, TPB, NSTATE * sizeof(float2), stream>>>(
        states, weights, head_w, head_b, out);
}

// Round 6
// 141.971 us; speedup vs baseline: 1.2360x; 1.2360x over previous
//
#include <hip/hip_runtime.h>
#include <math.h>

#define NW 14
#define NSTATE 16384           // 2^14 amplitudes
#define NL 4
#define BATCH 128
#define TPB 1024

// ---------------------------------------------------------------------------
// Index convention (round-1 PASSING kernel): wire i lives at bit (13-i).
//
// CNOT-ring composite: psi_new[idx] = psi_old[R(idx)],
//   R: y_p = x_p ^ x_{p+1} (p=0..11), y_12 = x12^x13^x0, y_13 = x13^x0.
// Scatter form: value at logical I goes to R^{-1}(I). Verified basis images:
//   R^{-1}(e_j) = ((2<<j)-1) | e13  (j<=11)   [suffix-xor + parity]
//   R^{-1}(e_12) = 0x3FFF, R^{-1}(e_13) = 0x1FFF.
// Useful: R^{-1}(e_10) = 0x27FF, R^{-1}(e_11) = 0x2FFF,
//         R^{-1}(e_12^e_13) = 0x2000.
//
// Register budget is the whole game (rounds 3-5: compiler caps at 64 VGPRs
// regardless of launch_bounds/waves_per_eu attrs; r[16]=32 VGPRs spilled to
// scratch -> 114 MB HBM/dispatch, kernel scratch-BW-bound at ~930 GB/s).
// This version keeps peak live ~13 float2 so 64 VGPRs suffice by construction:
//   - 4 passes of 3 index bits each (r[8]) per layer
//   - final 2-bit pass (bits 12,13) + perm: one cell parked in spare LDS.
// Bank conflicts measured at ~2% of runtime -> no swizzle, plain indexing.
// ---------------------------------------------------------------------------

#define B12_ 0x3FFFu
#define B13_ 0x1FFFu

// SU(2) gate [[a,b],[-b*,a*]], g={ar,ai,br,bi}, on register pairs (k, k|M).
template<int N, int M>
__device__ __forceinline__ void gateN(float2* r, const float4 g) {
#pragma unroll
    for (int k = 0; k < N; ++k) {
        if ((k & M) == 0) {
            const float x0 = r[k].x,   y0 = r[k].y;
            const float x1 = r[k|M].x, y1 = r[k|M].y;
            r[k].x   =  g.x*x0 - g.y*y0 + g.z*x1 - g.w*y1;
            r[k].y   =  g.x*y0 + g.y*x0 + g.z*y1 + g.w*x1;
            r[k|M].x = -g.z*x0 - g.w*y0 + g.x*x1 + g.y*y1;
            r[k|M].y = -g.z*y0 + g.w*x0 + g.x*y1 - g.y*x1;
        }
    }
}

// One pass: 3 gates on index bits [J0..J0+2] (wires 13-J0 .. 11-J0).
// Thread handles 16 amps as 2 iterations of 8-in-registers. In-place is safe
// without intra-pass barriers: each thread rewrites exactly the slots it read.
template<int J0>
__device__ __forceinline__ void pass3(float2* psi, const float4* gc4,
                                      int l, unsigned t) {
    const float4 gA = gc4[l*NW + (13-(J0+0))];
    const float4 gB = gc4[l*NW + (13-(J0+1))];
    const float4 gC = gc4[l*NW + (13-(J0+2))];
#pragma unroll
    for (int m = 0; m < 2; ++m) {
        const unsigned x    = t | ((unsigned)m << 10);   // 11 non-group bits
        const unsigned low  = x & ((1u << J0) - 1u);
        const unsigned high = (x >> J0) << (J0 + 3);
        float2 r[8];
#pragma unroll
        for (int k = 0; k < 8; ++k)
            r[k] = psi[low | ((unsigned)k << J0) | high];
        gateN<8,1>(r, gA);
        gateN<8,2>(r, gB);
        gateN<8,4>(r, gC);
#pragma unroll
        for (int k = 0; k < 8; ++k)
            psi[low | ((unsigned)k << J0) | high] = r[k];
    }
}

// Final pass of a layer: gates on index bits 12 (wire 1) and 13 (wire 0),
// then the CNOT-ring permutation folded into the scatter. Thread handles 4
// cells (base = t | m<<10, amps k<<12). Cell 0 is gated early and parked in
// spare LDS so only 3 cells (12 float2) stay live across the barrier.
__device__ __forceinline__ void passE(float2* psi, float2* spare,
                                      const float4* gc4, int l, unsigned t) {
    const float4 g1 = gc4[l*NW + 1];   // index bit 12 -> wire 1
    const float4 g0 = gc4[l*NW + 0];   // index bit 13 -> wire 0

    // Rinv of base t (bits only in 0..9): suffix-xor + parity -> bit 13.
    unsigned v = t;
    v ^= v >> 1; v ^= v >> 2; v ^= v >> 4; v ^= v >> 8;
    const unsigned Rinv0 = (v & 0x0FFFu) | ((v & 1u) << 13);

    // Cell 0: gather, gate, park 3 amps, keep 1.
    float2 c0[4];
#pragma unroll
    for (int k = 0; k < 4; ++k) c0[k] = psi[t | ((unsigned)k << 12)];
    gateN<4,1>(c0, g1);
    gateN<4,2>(c0, g0);
    spare[3*t+0] = c0[1];
    spare[3*t+1] = c0[2];
    spare[3*t+2] = c0[3];
    const float2 keep = c0[0];

    // Cells 1..3 in registers.
    float2 r[12];
#pragma unroll
    for (int m = 1; m < 4; ++m) {
        const unsigned base = t | ((unsigned)m << 10);
#pragma unroll
        for (int k = 0; k < 4; ++k)
            r[(m-1)*4 + k] = psi[base | ((unsigned)k << 12)];
    }
#pragma unroll
    for (int m = 0; m < 3; ++m) {
        gateN<4,1>(r + 4*m, g1);
        gateN<4,2>(r + 4*m, g0);
    }

    __syncthreads();   // all psi gathers done -> in-place scatter is safe

#pragma unroll
    for (int m = 1; m < 4; ++m) {
        // Rinv(t | m<<10) = Rinv0 ^ Rinv(m<<10) (GF(2)-linear).
        const unsigned Rb = Rinv0 ^ ((m & 1) ? 0x27FFu : 0u)
                                  ^ ((m & 2) ? 0x2FFFu : 0u);
#pragma unroll
        for (int k = 0; k < 4; ++k) {
            const unsigned CK = ((k & 1) ? B12_ : 0u) ^ ((k & 2) ? B13_ : 0u);
            psi[Rb ^ CK] = r[(m-1)*4 + k];
        }
    }
    psi[Rinv0]           = keep;          // cell 0, k=0
    psi[Rinv0 ^ B12_]    = spare[3*t+0];  // k=1
    psi[Rinv0 ^ B13_]    = spare[3*t+1];  // k=2
    psi[Rinv0 ^ 0x2000u] = spare[3*t+2];  // k=3 (B12_^B13_)
}

__global__ __launch_bounds__(TPB) void qsim_kernel(
    const float* __restrict__ states,
    const float* __restrict__ weights,
    const float* __restrict__ head_w,
    const float* __restrict__ head_b,
    float* __restrict__ out)
{
    extern __shared__ float2 dyn[];
    float2* psi   = dyn;            // 16384 float2 = 128 KB
    float2* spare = dyn + NSTATE;   //  3072 float2 =  24 KB
    __shared__ float4 gc4[NL * NW];
    __shared__ float wsum[TPB / 64];

    const int b = blockIdx.x;
    const unsigned tid = threadIdx.x;

    // One-time gate-coef precompute: G = RZ(t2)*RX(t1); layer 0 folds the
    // data-encoding RX(|x_w|) in (RX angles add). SU(2): a=g00, b=g01.
    if (tid < NL * NW) {
        const int l = (int)tid / NW, w = (int)tid % NW;
        float t1 = weights[tid * 2 + 0];
        float t2 = weights[tid * 2 + 1];
        if (l == 0) t1 += fabsf(states[(size_t)b * NSTATE + w]);
        float s, c, sz, cz;
        sincosf(0.5f * t1, &s, &c);
        sincosf(0.5f * t2, &sz, &cz);
        gc4[tid] = make_float4(c * cz, -c * sz, -s * sz, -s * cz);
    }
    // |0...0>
    for (unsigned i = tid; i < NSTATE; i += TPB)
        psi[i] = make_float2(i == 0 ? 1.0f : 0.0f, 0.0f);
    __syncthreads();

    for (int l = 0; l < NL; ++l) {
        pass3<0>(psi, gc4, l, tid);  __syncthreads();  // wires 13,12,11
        pass3<3>(psi, gc4, l, tid);  __syncthreads();  // wires 10, 9, 8
        pass3<6>(psi, gc4, l, tid);  __syncthreads();  // wires  7, 6, 5
        pass3<9>(psi, gc4, l, tid);  __syncthreads();  // wires  4, 3, 2
        passE(psi, spare, gc4, l, tid);  __syncthreads();  // wires 1,0 + ring
    }

    // out[b] = sum |amp|^2 * cv(idx) + head_b ; cv = sum_i hw[i]*(1-2*bit_i)
    float hw[NW];
#pragma unroll
    for (int i = 0; i < NW; ++i) hw[i] = head_w[i];

    // idx = tid + m*TPB: bits 0-9 = tid (wires 13..4), bits 10-13 = m
    // (wires 3,2,1,0). Precompute the tid part once.
    float cvlow = 0.0f;
#pragma unroll
    for (int i = 0; i < NW; ++i) cvlow += hw[i];
#pragma unroll
    for (int j = 0; j < 10; ++j)
        if ((tid >> j) & 1u) cvlow -= 2.0f * hw[13 - j];

    float acc = 0.0f;
#pragma unroll
    for (int m = 0; m < 16; ++m) {
        const float2 a = psi[tid + (unsigned)m * TPB];
        const float p = a.x * a.x + a.y * a.y;
        float cv = cvlow;
        if (m & 1) cv -= 2.0f * hw[3];
        if (m & 2) cv -= 2.0f * hw[2];
        if (m & 4) cv -= 2.0f * hw[1];
        if (m & 8) cv -= 2.0f * hw[0];
        acc += p * cv;
    }
#pragma unroll
    for (int off = 32; off > 0; off >>= 1)
        acc += __shfl_down(acc, off, 64);
    if ((tid & 63u) == 0) wsum[tid >> 6] = acc;
    __syncthreads();
    if (tid == 0) {
        float tot = 0.0f;
#pragma unroll
        for (int i = 0; i < TPB / 64; ++i) tot += wsum[i];
        out[b] = tot + head_b[0];
    }
}

extern "C" void kernel_launch(void* const* d_in, const int* in_sizes, int n_in,
                              void* d_out, int out_size, void* d_ws, size_t ws_size,
                              hipStream_t stream) {
    const float* states  = (const float*)d_in[0];  // (128, 16384)
    const float* weights = (const float*)d_in[1];  // (4, 14, 2)
    const float* head_w  = (const float*)d_in[2];  // (1, 14)
    const float* head_b  = (const float*)d_in[3];  // (1,)
    float* out = (float*)d_out;                    // (128,)
    const size_t shmem = (size_t)(NSTATE + 3 * TPB) * sizeof(float2);
    qsim_kernel<<<BATCH, TPB, shmem, stream>>>(
        states, weights, head_w, head_b, out);
}

// Round 7
// 140.574 us; speedup vs baseline: 1.2483x; 1.0099x over previous
//
#include <hip/hip_runtime.h>
#include <math.h>

#define NW 14
#define NSTATE 16384           // 2^14 amplitudes
#define NL 4
#define BATCH 128
#define TPB 1024

// ---------------------------------------------------------------------------
// Index convention: wire i lives at bit (13-i).
//
// CNOT-ring composite: psi_new[idx] = psi_old[R(idx)],
//   R: y_p = x_p ^ x_{p+1} (p=0..11), y_12 = x12^x13^x0, y_13 = x13^x0.
// Scatter form: value at logical I goes to R^{-1}(I). Verified basis images:
//   R^{-1}(e_j) = ((2<<j)-1) | e13  (j<=11), R^{-1}(e_12)=0x3FFF,
//   R^{-1}(e_13)=0x1FFF, R^{-1}(e_10)=0x27FF, R^{-1}(e_11)=0x2FFF,
//   R^{-1}(e_12^e_13)=0x2000.
//
// Register budget: compiler caps at 64 VGPRs (rounds 3-5: launch_bounds /
// waves_per_eu could not move it; r[16] spilled -> scratch-BW-bound).
// Structure keeps peak live ~13 float2: 4x 3-bit passes (r[8]) + final
// 2-bit pass with one cell parked in spare LDS.
//
// Bank conflicts (round 6: 8.5M cycles ~ 15us): passes J0=0 and J0=3 have
// their bank-pair index (idx mod 16) partly constant per instruction.
// Fix: XOR swizzle r[k] <-> logical j=k^s3 with s3 drawn from t bits that
// complete uniform bank coverage, plus the (round-3-verified) X*G*X sign
// conjugation: when s3&M, the register pair orientation is swapped ->
// apply [[a*,-b*],[b,a]] = negate (ai, br). J0=6/9 and passE already have
// bank bits 0-3 fed entirely by t bits 0-3 -> uniform, left unswizzled.
// ---------------------------------------------------------------------------

#define B12_ 0x3FFFu
#define B13_ 0x1FFFu

// SU(2) gate [[a,b],[-b*,a*]], g={ar,ai,br,bi}, on register pairs (k, k|M).
// s3&M -> conjugate by X (swapped orientation): negate ai, br.
template<int N, int M>
__device__ __forceinline__ void gateN(float2* r, float4 g, unsigned s3) {
    const float f = (s3 & (unsigned)M) ? -1.0f : 1.0f;
    g.y *= f;
    g.z *= f;
#pragma unroll
    for (int k = 0; k < N; ++k) {
        if ((k & M) == 0) {
            const float x0 = r[k].x,   y0 = r[k].y;
            const float x1 = r[k|M].x, y1 = r[k|M].y;
            r[k].x   =  g.x*x0 - g.y*y0 + g.z*x1 - g.w*y1;
            r[k].y   =  g.x*y0 + g.y*x0 + g.z*y1 + g.w*x1;
            r[k|M].x = -g.z*x0 - g.w*y0 + g.x*x1 + g.y*y1;
            r[k|M].y = -g.z*y0 + g.w*x0 + g.x*y1 - g.y*x1;
        }
    }
}

// One pass: 3 gates on index bits [J0..J0+2]. Thread handles 16 amps as 2
// iterations of 8-in-registers; slots are thread-private within a pass.
// S3SRC selects the swizzle source: register k holds logical j = k ^ s3.
template<int J0, int S3SH, int S3MSK>
__device__ __forceinline__ void pass3(float2* psi, const float4* gc4,
                                      int l, unsigned t) {
    const float4 gA = gc4[l*NW + (13-(J0+0))];
    const float4 gB = gc4[l*NW + (13-(J0+1))];
    const float4 gC = gc4[l*NW + (13-(J0+2))];
    const unsigned s3 = (t >> S3SH) & (unsigned)S3MSK;
#pragma unroll
    for (int m = 0; m < 2; ++m) {
        const unsigned x    = t | ((unsigned)m << 10);   // 11 non-group bits
        const unsigned low  = x & ((1u << J0) - 1u);
        const unsigned high = (x >> J0) << (J0 + 3);
        float2 r[8];
#pragma unroll
        for (int k = 0; k < 8; ++k)
            r[k] = psi[low | (((unsigned)k ^ s3) << J0) | high];
        gateN<8,1>(r, gA, s3);
        gateN<8,2>(r, gB, s3);
        gateN<8,4>(r, gC, s3);
#pragma unroll
        for (int k = 0; k < 8; ++k)
            psi[low | (((unsigned)k ^ s3) << J0) | high] = r[k];
    }
}

// Final pass of a layer: gates on index bits 12 (wire 1), 13 (wire 0), then
// the CNOT-ring permutation folded into the scatter. Thread handles 4 cells
// (base = t | m<<10, amps k<<12). Cell 0 is gated early and parked in spare
// LDS so only ~13 float2 stay live across the barrier.
__device__ __forceinline__ void passE(float2* psi, float2* spare,
                                      const float4* gc4, int l, unsigned t) {
    const float4 g1 = gc4[l*NW + 1];   // index bit 12 -> wire 1
    const float4 g0 = gc4[l*NW + 0];   // index bit 13 -> wire 0

    // Rinv of base t (bits only in 0..9): suffix-xor + parity -> bit 13.
    unsigned v = t;
    v ^= v >> 1; v ^= v >> 2; v ^= v >> 4; v ^= v >> 8;
    const unsigned Rinv0 = (v & 0x0FFFu) | ((v & 1u) << 13);

    // Cell 0: gather, gate, park 3 amps, keep 1.
    float2 c0[4];
#pragma unroll
    for (int k = 0; k < 4; ++k) c0[k] = psi[t | ((unsigned)k << 12)];
    gateN<4,1>(c0, g1, 0u);
    gateN<4,2>(c0, g0, 0u);
    spare[3*t+0] = c0[1];
    spare[3*t+1] = c0[2];
    spare[3*t+2] = c0[3];
    const float2 keep = c0[0];

    // Cells 1..3 in registers.
    float2 r[12];
#pragma unroll
    for (int m = 1; m < 4; ++m) {
        const unsigned base = t | ((unsigned)m << 10);
#pragma unroll
        for (int k = 0; k < 4; ++k)
            r[(m-1)*4 + k] = psi[base | ((unsigned)k << 12)];
    }
#pragma unroll
    for (int m = 0; m < 3; ++m) {
        gateN<4,1>(r + 4*m, g1, 0u);
        gateN<4,2>(r + 4*m, g0, 0u);
    }

    __syncthreads();   // all psi gathers done -> in-place scatter is safe

#pragma unroll
    for (int m = 1; m < 4; ++m) {
        // Rinv(t | m<<10) = Rinv0 ^ Rinv(m<<10) (GF(2)-linear).
        const unsigned Rb = Rinv0 ^ ((m & 1) ? 0x27FFu : 0u)
                                  ^ ((m & 2) ? 0x2FFFu : 0u);
#pragma unroll
        for (int k = 0; k < 4; ++k) {
            const unsigned CK = ((k & 1) ? B12_ : 0u) ^ ((k & 2) ? B13_ : 0u);
            psi[Rb ^ CK] = r[(m-1)*4 + k];
        }
    }
    psi[Rinv0]           = keep;          // cell 0, k=0
    psi[Rinv0 ^ B12_]    = spare[3*t+0];  // k=1
    psi[Rinv0 ^ B13_]    = spare[3*t+1];  // k=2
    psi[Rinv0 ^ 0x2000u] = spare[3*t+2];  // k=3 (B12_^B13_)
}

__global__ __launch_bounds__(TPB) void qsim_kernel(
    const float* __restrict__ states,
    const float* __restrict__ weights,
    const float* __restrict__ head_w,
    const float* __restrict__ head_b,
    float* __restrict__ out)
{
    extern __shared__ float2 dyn[];
    float2* psi   = dyn;            // 16384 float2 = 128 KB
    float2* spare = dyn + NSTATE;   //  3072 float2 =  24 KB
    __shared__ float4 gc4[NL * NW];
    __shared__ float wsum[TPB / 64];

    const int b = blockIdx.x;
    const unsigned tid = threadIdx.x;

    // One-time gate-coef precompute: G = RZ(t2)*RX(t1); layer 0 folds the
    // data-encoding RX(|x_w|) in (RX angles add). SU(2): a=g00, b=g01.
    if (tid < NL * NW) {
        const int l = (int)tid / NW, w = (int)tid % NW;
        float t1 = weights[tid * 2 + 0];
        float t2 = weights[tid * 2 + 1];
        if (l == 0) t1 += fabsf(states[(size_t)b * NSTATE + w]);
        float s, c, sz, cz;
        sincosf(0.5f * t1, &s, &c);
        sincosf(0.5f * t2, &sz, &cz);
        gc4[tid] = make_float4(c * cz, -c * sz, -s * sz, -s * cz);
    }
    // |0...0>
    for (unsigned i = tid; i < NSTATE; i += TPB)
        psi[i] = make_float2(i == 0 ? 1.0f : 0.0f, 0.0f);
    __syncthreads();

    for (int l = 0; l < NL; ++l) {
        // J0=0: bank-pair = (k^s3) + 8*(t&1) -> s3=(t>>1)&7 makes lanes
        // 0..15 cover all 16 pairs once (uniform, BW-floor).
        pass3<0, 1, 7>(psi, gc4, l, tid);  __syncthreads();  // wires 13,12,11
        // J0=3: bank-pair = (t&7) + 8*((k^s3)&1) -> s3=(t>>3)&1 uniform.
        pass3<3, 3, 1>(psi, gc4, l, tid);  __syncthreads();  // wires 10, 9, 8
        // J0=6/9: bank bits fully from t bits 0-3 -> already uniform.
        pass3<6, 0, 0>(psi, gc4, l, tid);  __syncthreads();  // wires  7, 6, 5
        pass3<9, 0, 0>(psi, gc4, l, tid);  __syncthreads();  // wires  4, 3, 2
        passE(psi, spare, gc4, l, tid);    __syncthreads();  // wires 1,0 + ring
    }

    // out[b] = sum |amp|^2 * cv(idx) + head_b ; cv = sum_i hw[i]*(1-2*bit_i)
    float hw[NW];
#pragma unroll
    for (int i = 0; i < NW; ++i) hw[i] = head_w[i];

    // idx = tid + m*TPB: bits 0-9 = tid (wires 13..4), bits 10-13 = m
    // (wires 3,2,1,0). Precompute the tid part once.
    float cvlow = 0.0f;
#pragma unroll
    for (int i = 0; i < NW; ++i) cvlow += hw[i];
#pragma unroll
    for (int j = 0; j < 10; ++j)
        if ((tid >> j) & 1u) cvlow -= 2.0f * hw[13 - j];

    float acc = 0.0f;
#pragma unroll
    for (int m = 0; m < 16; ++m) {
        const float2 a = psi[tid + (unsigned)m * TPB];
        const float p = a.x * a.x + a.y * a.y;
        float cv = cvlow;
        if (m & 1) cv -= 2.0f * hw[3];
        if (m & 2) cv -= 2.0f * hw[2];
        if (m & 4) cv -= 2.0f * hw[1];
        if (m & 8) cv -= 2.0f * hw[0];
        acc += p * cv;
    }
#pragma unroll
    for (int off = 32; off > 0; off >>= 1)
        acc += __shfl_down(acc, off, 64);
    if ((tid & 63u) == 0) wsum[tid >> 6] = acc;
    __syncthreads();
    if (tid == 0) {
        float tot = 0.0f;
#pragma unroll
        for (int i = 0; i < TPB / 64; ++i) tot += wsum[i];
        out[b] = tot + head_b[0];
    }
}

extern "C" void kernel_launch(void* const* d_in, const int* in_sizes, int n_in,
                              void* d_out, int out_size, void* d_ws, size_t ws_size,
                              hipStream_t stream) {
    const float* states  = (const float*)d_in[0];  // (128, 16384)
    const float* weights = (const float*)d_in[1];  // (4, 14, 2)
    const float* head_w  = (const float*)d_in[2];  // (1, 14)
    const float* head_b  = (const float*)d_in[3];  // (1,)
    float* out = (float*)d_out;                    // (128,)
    const size_t shmem = (size_t)(NSTATE + 3 * TPB) * sizeof(float2);
    qsim_kernel<<<BATCH, TPB, shmem, stream>>>(
        states, weights, head_w, head_b, out);
}

// Round 8
// 123.715 us; speedup vs baseline: 1.4184x; 1.1363x over previous
//
#include <hip/hip_runtime.h>
#include <math.h>

#define NW 14
#define NSTATE 16384
#define HALF 8192
#define NL 4
#define BATCH 128
#define TPB 1024
#define SHBYTES (84 * 1024)   // > 80 KB forces 1 block/CU (LDS=160 KB/CU)

// ---------------------------------------------------------------------------
// Wire w <-> index bit (13-w).  CNOT-ring composite (verified r1):
//   psi_new[I] = psi_old[R(I)];  R: y_p = x_p^x_{p+1} (p<=11),
//   y12 = x12^x13^x0, y13 = x13^x0.
// Rinv basis (verified): Rinv(e_j) = ((2<<j)-1)|e13 (j<=11),
//   Rinv(e12)=0x3FFF, Rinv(e13)=0x1FFF.
//
// 256-block split: block gid = q*128+b holds half-state bit13=q (8192 amps,
// 64 KB LDS) -> all 256 CUs active (round-7 ceiling was 128 CUs busy).
// Global scratch holds the state RELABELED by Rinv: slot[s] = pre_perm[R(s)].
//   - boundary read: block reads its own contiguous slice; the deferred
//     wire-0 gate (split bit) pairs slot I with slot I^0x1FFF (same slice).
//     Gate row r = (R(I))_13 = I_13 ^ I_0 = q ^ bit0(I).
//   - boundary write: scatter to Rinv(J) (suffix-xor map) with the wire-1
//     (bit12) gate folded in; cross-half exchange happens here via the
//     parity bit of Rinv.
// Layer 0 (encoding RX + RX/RZ, all before first CNOT) is a PRODUCT state:
// synthesized from two tables, no passes needed.
// Register budget: compiler caps at 64 VGPRs (r3-r5 immovable); all loops
// keep <= ~10 float2 live.
// ---------------------------------------------------------------------------

__device__ __forceinline__ unsigned sxmap(unsigned v) {   // v: bits 0..11
    unsigned t = v;
    t ^= t >> 1; t ^= t >> 2; t ^= t >> 4; t ^= t >> 8;
    return (t & 0x0FFFu) | ((t & 1u) << 13);              // = Rinv(v)
}

__device__ __forceinline__ float2 cmul(float2 u, float2 v) {
    return make_float2(u.x * v.x - u.y * v.y, u.x * v.y + u.y * v.x);
}

// Fused 1q gate G = RZ(t2)*RX(t1), SU(2) [[a,b],[-b*,a*]], ret {ar,ai,br,bi}.
// Layer 0 folds the data-encoding RX(|x_w|) (RX angles add; verified r1-r7).
__device__ __forceinline__ float4 fused_coef(const float* weights,
                                             const float* states,
                                             int b, int l, int w) {
    float t1 = weights[(l * NW + w) * 2 + 0];
    float t2 = weights[(l * NW + w) * 2 + 1];
    if (l == 0) t1 += fabsf(states[(size_t)b * NSTATE + w]);
    float s, c, sz, cz;
    sincosf(0.5f * t1, &s, &c);
    sincosf(0.5f * t2, &sz, &cz);
    return make_float4(c * cz, -c * sz, -s * sz, -s * cz);
}

// SU(2) gate on register pairs (k,k|M); register k holds logical j=k^s3;
// when s3&M the orientation is swapped -> apply X*G*X = negate (ai,br).
// (Verified rounds 3-7.)
template<int N, int M>
__device__ __forceinline__ void gateN(float2* r, float4 g, unsigned s3) {
    const float f = (s3 & (unsigned)M) ? -1.0f : 1.0f;
    g.y *= f;
    g.z *= f;
#pragma unroll
    for (int k = 0; k < N; ++k) {
        if ((k & M) == 0) {
            const float x0 = r[k].x,   y0 = r[k].y;
            const float x1 = r[k|M].x, y1 = r[k|M].y;
            r[k].x   =  g.x*x0 - g.y*y0 + g.z*x1 - g.w*y1;
            r[k].y   =  g.x*y0 + g.y*x0 + g.z*y1 + g.w*x1;
            r[k|M].x = -g.z*x0 - g.w*y0 + g.x*x1 + g.y*y1;
            r[k|M].y = -g.z*y0 + g.w*x0 + g.x*y1 - g.y*x1;
        }
    }
}

// 3-bit in-LDS pass over a 13-bit half-state; t = tid (10 bits), one r[8]
// iteration. Swizzle params per round-7 bank analysis (J0=0: s3=(t>>1)&7;
// J0=3: s3=(t>>3)&1; J0=6/9 conflict-free unswizzled).
template<int J0, int S3SH, int S3MSK>
__device__ __forceinline__ void pass3(float2* psi, const float4* gc,
                                      unsigned t) {
    const float4 gA = gc[13 - (J0 + 0)];
    const float4 gB = gc[13 - (J0 + 1)];
    const float4 gC = gc[13 - (J0 + 2)];
    const unsigned s3   = (t >> S3SH) & (unsigned)S3MSK;
    const unsigned low  = t & ((1u << J0) - 1u);
    const unsigned high = (t >> J0) << (J0 + 3);
    float2 r[8];
#pragma unroll
    for (int k = 0; k < 8; ++k)
        r[k] = psi[low | (((unsigned)k ^ s3) << J0) | high];
    gateN<8,1>(r, gA, s3);
    gateN<8,2>(r, gB, s3);
    gateN<8,4>(r, gC, s3);
#pragma unroll
    for (int k = 0; k < 8; ++k)
        psi[low | (((unsigned)k ^ s3) << J0) | high] = r[k];
}

// K_init: synthesize layer-0 product state (wires 1..13 gated; wire 0
// deferred to next kernel's entry) and scatter Rinv-relabeled to SA.
__global__ __launch_bounds__(TPB) void k_init(
    const float* __restrict__ states, const float* __restrict__ weights,
    float2* __restrict__ SA)
{
    extern __shared__ float2 dyn[];   // occupancy pad only
    __shared__ float2 vfac[NW][2];    // per-wire (a, -b*) = G|0>
    __shared__ float2 T1[128];        // product over bits 0-6  (wires 13..7)
    __shared__ float2 T2[64];         // product over bits 7-12 (wires 6..1)
    const unsigned gid = blockIdx.x, q = gid >> 7, b = gid & 127u;
    const unsigned tid = threadIdx.x;
    (void)dyn;

    if (tid < NW) {
        float4 g = fused_coef(weights, states, (int)b, 0, (int)tid);
        vfac[tid][0] = make_float2(g.x, g.y);
        vfac[tid][1] = make_float2(-g.z, g.w);
    }
    __syncthreads();
    if (tid < 128) {
        float2 p = make_float2(1.0f, 0.0f);
#pragma unroll
        for (int pb = 0; pb < 7; ++pb)
            p = cmul(p, vfac[13 - pb][(tid >> pb) & 1u]);
        T1[tid] = p;
    } else if (tid < 192) {
        const unsigned m = tid - 128;
        float2 p = make_float2(1.0f, 0.0f);
#pragma unroll
        for (int pb = 7; pb < 13; ++pb)
            p = cmul(p, vfac[13 - pb][(m >> (pb - 7)) & 1u]);
        T2[m] = p;
    }
    __syncthreads();

    float2* dst = SA + (size_t)b * NSTATE;
#pragma unroll
    for (int k = 0; k < 8; ++k) {
        const unsigned jl = tid + (unsigned)k * TPB;   // bits 0..12
        float2 amp = make_float2(0.0f, 0.0f);
        if (q == 0)                                    // wire0 still |0>
            amp = cmul(T1[jl & 127u], T2[(jl >> 7) & 63u]);
        const unsigned d = sxmap(jl & 0x0FFFu)
                         ^ ((jl & 0x1000u) ? 0x3FFFu : 0u)
                         ^ (q ? 0x1FFFu : 0u);
        dst[d] = amp;
    }
}

// K_layer<L>: entry = read own slice + wire-0 gate of layer L-1 (pairs
// I, I^0x1FFF; row = q^bit0) -> LDS; 4 local passes (layer-L wires 13..2);
// exit = wire-1 gate (bit12) + Rinv relabel scatter to Sout.
template<int L>
__global__ __launch_bounds__(TPB) void k_layer(
    const float* __restrict__ states, const float* __restrict__ weights,
    const float2* __restrict__ Sin, float2* __restrict__ Sout)
{
    extern __shared__ float2 psi[];   // HALF float2 = 64 KB (84 KB requested)
    __shared__ float4 gc[NW];
    __shared__ float4 ge_s;
    const unsigned gid = blockIdx.x, q = gid >> 7, b = gid & 127u;
    const unsigned tid = threadIdx.x;

    if (tid < NW) gc[tid] = fused_coef(weights, states, (int)b, L, (int)tid);
    if (tid == NW) ge_s = fused_coef(weights, states, (int)b, L - 1, 0);
    __syncthreads();
    const float4 ge = ge_s;

    const float2* src = Sin + (size_t)b * NSTATE + (size_t)q * HALF;
#pragma unroll
    for (int m = 0; m < 4; ++m) {
        const unsigned ic = tid + (unsigned)m * TPB;   // bit12 = 0
        const float2 f0 = src[ic];
        const float2 f1 = src[ic ^ 0x1FFFu];
        const unsigned rc = (q ^ ic) & 1u;
        const float aar = ge.x, aai = rc ? -ge.y : ge.y;
        const float bbr = rc ? -ge.z : ge.z, bbi = ge.w;
        float2 oc, op;   // oc = aa*f0 + bb*f1 ; op = conj(aa)*f1 - conj(bb)*f0
        oc.x = aar*f0.x - aai*f0.y + bbr*f1.x - bbi*f1.y;
        oc.y = aar*f0.y + aai*f0.x + bbr*f1.y + bbi*f1.x;
        op.x = aar*f1.x + aai*f1.y - (bbr*f0.x + bbi*f0.y);
        op.y = aar*f1.y - aai*f1.x - (bbr*f0.y - bbi*f0.x);
        psi[ic]           = oc;
        psi[ic ^ 0x1FFFu] = op;
    }
    __syncthreads();

    pass3<0, 1, 7>(psi, gc, tid);  __syncthreads();  // wires 13,12,11
    pass3<3, 3, 1>(psi, gc, tid);  __syncthreads();  // wires 10, 9, 8
    pass3<6, 0, 0>(psi, gc, tid);  __syncthreads();  // wires  7, 6, 5
    pass3<9, 0, 0>(psi, gc, tid);  __syncthreads();  // wires  4, 3, 2

    const float4 g1 = gc[1];                          // wire 1 (bit12)
    float2* dst = Sout + (size_t)b * NSTATE;
#pragma unroll
    for (int m = 0; m < 4; ++m) {
        const unsigned jc = tid + (unsigned)m * TPB;  // bits 0..11
        const float2 x0 = psi[jc];
        const float2 x1 = psi[jc | 0x1000u];
        float2 A0, A1;
        A0.x =  g1.x*x0.x - g1.y*x0.y + g1.z*x1.x - g1.w*x1.y;
        A0.y =  g1.x*x0.y + g1.y*x0.x + g1.z*x1.y + g1.w*x1.x;
        A1.x = -g1.z*x0.x - g1.w*x0.y + g1.x*x1.x + g1.y*x1.y;
        A1.y = -g1.z*x0.y + g1.w*x0.x + g1.x*x1.y - g1.y*x1.x;
        const unsigned d0 = sxmap(jc) ^ (q ? 0x1FFFu : 0u);
        dst[d0]           = A0;
        dst[d0 ^ 0x3FFFu] = A1;   // ^Rinv(e12)
    }
}

// K_final: entry gate (layer-3 wire 0) + <Z> contraction + head, atomicAdd.
__global__ __launch_bounds__(TPB) void k_final(
    const float* __restrict__ states, const float* __restrict__ weights,
    const float* __restrict__ head_w, const float* __restrict__ head_b,
    const float2* __restrict__ Sin, float* __restrict__ out)
{
    extern __shared__ float2 dyn[];   // occupancy pad only
    __shared__ float4 ge_s;
    __shared__ float wsum[TPB / 64];
    const unsigned gid = blockIdx.x, q = gid >> 7, b = gid & 127u;
    const unsigned tid = threadIdx.x;
    (void)dyn;

    if (tid == 0) ge_s = fused_coef(weights, states, (int)b, NL - 1, 0);
    __syncthreads();
    const float4 ge = ge_s;

    float hw[NW];
#pragma unroll
    for (int i = 0; i < NW; ++i) hw[i] = head_w[i];

    // cv(I) = sum_w hw[w]*(1-2*bit_{13-w}(I)); Ic = q<<13 | ic, ic bit12=0.
    float cvbase = 0.0f;
#pragma unroll
    for (int i = 0; i < NW; ++i) cvbase += hw[i];
    if (q) cvbase -= 2.0f * hw[0];
#pragma unroll
    for (int p = 0; p < 10; ++p)
        if ((tid >> p) & 1u) cvbase -= 2.0f * hw[13 - p];
    const float s0w = 1.0f - 2.0f * (float)q;   // wire-0 sign (shared by pair)

    const float2* src = Sin + (size_t)b * NSTATE + (size_t)q * HALF;
    float acc = 0.0f;
#pragma unroll
    for (int m = 0; m < 4; ++m) {
        const unsigned ic = tid + (unsigned)m * TPB;
        const float2 f0 = src[ic];
        const float2 f1 = src[ic ^ 0x1FFFu];
        const unsigned rc = (q ^ ic) & 1u;
        const float aar = ge.x, aai = rc ? -ge.y : ge.y;
        const float bbr = rc ? -ge.z : ge.z, bbi = ge.w;
        float2 oc, op;
        oc.x = aar*f0.x - aai*f0.y + bbr*f1.x - bbi*f1.y;
        oc.y = aar*f0.y + aai*f0.x + bbr*f1.y + bbi*f1.x;
        op.x = aar*f1.x + aai*f1.y - (bbr*f0.x + bbi*f0.y);
        op.y = aar*f1.y - aai*f1.x - (bbr*f0.y - bbi*f0.x);
        float cv_c = cvbase;
        if (m & 1) cv_c -= 2.0f * hw[3];
        if (m & 2) cv_c -= 2.0f * hw[2];
        // partner flips wires 1..13, keeps wire 0:
        const float cv_p = 2.0f * hw[0] * s0w - cv_c;
        acc += (oc.x*oc.x + oc.y*oc.y) * cv_c
             + (op.x*op.x + op.y*op.y) * cv_p;
    }
#pragma unroll
    for (int off = 32; off > 0; off >>= 1)
        acc += __shfl_down(acc, off, 64);
    if ((tid & 63u) == 0) wsum[tid >> 6] = acc;
    __syncthreads();
    if (tid == 0) {
        float tot = 0.0f;
#pragma unroll
        for (int i = 0; i < TPB / 64; ++i) tot += wsum[i];
        if (q == 0) tot += head_b[0];   // head_b exactly once per sample
        atomicAdd(out + b, tot);
    }
}

extern "C" void kernel_launch(void* const* d_in, const int* in_sizes, int n_in,
                              void* d_out, int out_size, void* d_ws, size_t ws_size,
                              hipStream_t stream) {
    const float* states  = (const float*)d_in[0];  // (128, 16384)
    const float* weights = (const float*)d_in[1];  // (4, 14, 2)
    const float* head_w  = (const float*)d_in[2];  // (1, 14)
    const float* head_b  = (const float*)d_in[3];  // (1,)
    float* out = (float*)d_out;                    // (128,)

    float2* SA = (float2*)d_ws;                    // 16 MB
    float2* SB = SA + (size_t)BATCH * NSTATE;      // 16 MB  (ws >= 32 MB)

    hipMemsetAsync(out, 0, BATCH * sizeof(float), stream);
    k_init    <<<2 * BATCH, TPB, SHBYTES, stream>>>(states, weights, SA);
    k_layer<1><<<2 * BATCH, TPB, SHBYTES, stream>>>(states, weights, SA, SB);
    k_layer<2><<<2 * BATCH, TPB, SHBYTES, stream>>>(states, weights, SB, SA);
    k_layer<3><<<2 * BATCH, TPB, SHBYTES, stream>>>(states, weights, SA, SB);
    k_final   <<<2 * BATCH, TPB, SHBYTES, stream>>>(states, weights, head_w,
                                                    head_b, SB, out);
}

// Round 9
// 114.676 us; speedup vs baseline: 1.5303x; 1.0788x over previous
//
#include <hip/hip_runtime.h>
#include <math.h>

#define NW 14
#define NSTATE 16384
#define HALF 8192
#define NL 4
#define BATCH 128
#define TPB 1024
#define SHBYTES (84 * 1024)   // > 80 KB forces 1 block/CU (LDS=160 KB/CU)

// ---------------------------------------------------------------------------
// Wire w <-> index bit (13-w).  CNOT-ring composite (verified r1):
//   psi_new[I] = psi_old[R(I)];  R: y_p = x_p^x_{p+1} (p<=11),
//   y12 = x12^x13^x0, y13 = x13^x0.
// Rinv basis (verified): Rinv(e_j)=((2<<j)-1)|e13 (j<=11), Rinv(e12)=0x3FFF,
//   Rinv(e13)=0x1FFF.
//
// 256-block split (r8, verified): block gid = q*128+b holds half-state
// bit13=q (8192 amps, 64 KB LDS). Global scratch holds the state RELABELED
// by Rinv: slot[s] = pre_perm[R(s)]. Boundary read: contiguous own slice +
// deferred wire-0 gate pairs (I, I^0x1FFF), row = q^bit0(I). Boundary
// write: wire-1 (bit12) gate + scatter to Rinv labels.
//
// r9 changes (structure only, same algebra):
//  - k_init eliminated: layer-0 output is a PRODUCT state, so k_layer1
//    synthesizes its own half directly in LDS as amp(I) = T1[J&127] *
//    T2[J>>7] with J = R(q<<13|I)  (perm folded into table lookup).
//  - k_final: one block per sample (128 blocks), both halves, direct
//    out[b] write -> no memset, no atomics, no LDS pad.
// Register budget: compiler caps at 64 VGPRs (r3-r5 immovable); loops keep
// <= ~10 float2 live. Swizzle params per r7 bank analysis.
// ---------------------------------------------------------------------------

__device__ __forceinline__ unsigned sxmap(unsigned v) {   // v: bits 0..11
    unsigned t = v;
    t ^= t >> 1; t ^= t >> 2; t ^= t >> 4; t ^= t >> 8;
    return (t & 0x0FFFu) | ((t & 1u) << 13);              // = Rinv(v)
}

__device__ __forceinline__ float2 cmul(float2 u, float2 v) {
    return make_float2(u.x * v.x - u.y * v.y, u.x * v.y + u.y * v.x);
}

// Fused 1q gate G = RZ(t2)*RX(t1), SU(2) [[a,b],[-b*,a*]], ret {ar,ai,br,bi}.
// Layer 0 folds the data-encoding RX(|x_w|) (RX angles add; verified r1-r8).
__device__ __forceinline__ float4 fused_coef(const float* weights,
                                             const float* states,
                                             int b, int l, int w) {
    float t1 = weights[(l * NW + w) * 2 + 0];
    float t2 = weights[(l * NW + w) * 2 + 1];
    if (l == 0) t1 += fabsf(states[(size_t)b * NSTATE + w]);
    float s, c, sz, cz;
    sincosf(0.5f * t1, &s, &c);
    sincosf(0.5f * t2, &sz, &cz);
    return make_float4(c * cz, -c * sz, -s * sz, -s * cz);
}

// SU(2) gate on register pairs (k,k|M); register k holds logical j=k^s3;
// when s3&M the orientation is swapped -> apply X*G*X = negate (ai,br).
template<int N, int M>
__device__ __forceinline__ void gateN(float2* r, float4 g, unsigned s3) {
    const float f = (s3 & (unsigned)M) ? -1.0f : 1.0f;
    g.y *= f;
    g.z *= f;
#pragma unroll
    for (int k = 0; k < N; ++k) {
        if ((k & M) == 0) {
            const float x0 = r[k].x,   y0 = r[k].y;
            const float x1 = r[k|M].x, y1 = r[k|M].y;
            r[k].x   =  g.x*x0 - g.y*y0 + g.z*x1 - g.w*y1;
            r[k].y   =  g.x*y0 + g.y*x0 + g.z*y1 + g.w*x1;
            r[k|M].x = -g.z*x0 - g.w*y0 + g.x*x1 + g.y*y1;
            r[k|M].y = -g.z*y0 + g.w*x0 + g.x*y1 - g.y*x1;
        }
    }
}

// 3-bit in-LDS pass over the 13-bit half-state (t = tid, 10 bits).
template<int J0, int S3SH, int S3MSK>
__device__ __forceinline__ void pass3(float2* psi, const float4* gc,
                                      unsigned t) {
    const float4 gA = gc[13 - (J0 + 0)];
    const float4 gB = gc[13 - (J0 + 1)];
    const float4 gC = gc[13 - (J0 + 2)];
    const unsigned s3   = (t >> S3SH) & (unsigned)S3MSK;
    const unsigned low  = t & ((1u << J0) - 1u);
    const unsigned high = (t >> J0) << (J0 + 3);
    float2 r[8];
#pragma unroll
    for (int k = 0; k < 8; ++k)
        r[k] = psi[low | (((unsigned)k ^ s3) << J0) | high];
    gateN<8,1>(r, gA, s3);
    gateN<8,2>(r, gB, s3);
    gateN<8,4>(r, gC, s3);
#pragma unroll
    for (int k = 0; k < 8; ++k)
        psi[low | (((unsigned)k ^ s3) << J0) | high] = r[k];
}

// Shared exit: wire-1 (bit12) gate + Rinv-relabel scatter to Sout.
__device__ __forceinline__ void exit_scatter(const float2* psi,
                                             float2* __restrict__ dst,
                                             float4 g1, unsigned q,
                                             unsigned tid) {
#pragma unroll
    for (int m = 0; m < 4; ++m) {
        const unsigned jc = tid + (unsigned)m * TPB;  // bits 0..11
        const float2 x0 = psi[jc];
        const float2 x1 = psi[jc | 0x1000u];
        float2 A0, A1;
        A0.x =  g1.x*x0.x - g1.y*x0.y + g1.z*x1.x - g1.w*x1.y;
        A0.y =  g1.x*x0.y + g1.y*x0.x + g1.z*x1.y + g1.w*x1.x;
        A1.x = -g1.z*x0.x - g1.w*x0.y + g1.x*x1.x + g1.y*x1.y;
        A1.y = -g1.z*x0.y + g1.w*x0.x + g1.x*x1.y - g1.y*x1.x;
        const unsigned d0 = sxmap(jc) ^ (q ? 0x1FFFu : 0u);
        dst[d0]           = A0;
        dst[d0 ^ 0x3FFFu] = A1;   // ^Rinv(e12)
    }
}

// K_layer1: synthesize post-ring layer-0 state directly (product state
// evaluated at J = R(I_full)), then layer-1 local passes + exit.
__global__ __launch_bounds__(TPB) void k_layer1(
    const float* __restrict__ states, const float* __restrict__ weights,
    float2* __restrict__ Sout)
{
    extern __shared__ float2 psi[];   // HALF float2 = 64 KB (84 KB requested)
    __shared__ float2 vfac[NW][2];    // per-wire G|0> components
    __shared__ float2 T1[128];        // product over J bits 0-6 (wires 13..7)
    __shared__ float2 T2[128];        // product over J bits 7-13 (wires 6..0)
    __shared__ float4 gc[NW];
    const unsigned gid = blockIdx.x, q = gid >> 7, b = gid & 127u;
    const unsigned tid = threadIdx.x;

    if (tid < NW) {
        float4 g = fused_coef(weights, states, (int)b, 0, (int)tid);
        vfac[tid][0] = make_float2(g.x, g.y);    // amp for bit=0 (g00)
        vfac[tid][1] = make_float2(-g.z, g.w);   // amp for bit=1 (g10=-b*)
    }
    if (tid >= 64 && tid < 64 + NW)
        gc[tid - 64] = fused_coef(weights, states, (int)b, 1, (int)(tid - 64));
    __syncthreads();
    if (tid < 128) {
        float2 p = make_float2(1.0f, 0.0f);
#pragma unroll
        for (int j = 0; j < 7; ++j)
            p = cmul(p, vfac[13 - j][(tid >> j) & 1u]);
        T1[tid] = p;
    } else if (tid < 256) {
        const unsigned u = tid - 128;
        float2 p = make_float2(1.0f, 0.0f);
#pragma unroll
        for (int j = 7; j < 14; ++j)
            p = cmul(p, vfac[13 - j][(u >> (j - 7)) & 1u]);
        T2[u] = p;
    }
    __syncthreads();

    // psi[I] = product-state amplitude at J = R(q<<13 | I).
#pragma unroll
    for (int m = 0; m < 8; ++m) {
        const unsigned I  = tid + (unsigned)m * TPB;        // 13-bit
        const unsigned If = I | (q << 13);
        const unsigned lo = (If ^ (If >> 1)) & 0x0FFFu;
        const unsigned y12 = ((If >> 12) ^ (If >> 13) ^ If) & 1u;
        const unsigned y13 = ((If >> 13) ^ If) & 1u;
        const unsigned J = lo | (y12 << 12) | (y13 << 13);
        psi[I] = cmul(T1[J & 127u], T2[J >> 7]);
    }
    __syncthreads();

    pass3<0, 1, 7>(psi, gc, tid);  __syncthreads();  // wires 13,12,11
    pass3<3, 3, 1>(psi, gc, tid);  __syncthreads();  // wires 10, 9, 8
    pass3<6, 0, 0>(psi, gc, tid);  __syncthreads();  // wires  7, 6, 5
    pass3<9, 0, 0>(psi, gc, tid);  __syncthreads();  // wires  4, 3, 2

    exit_scatter(psi, Sout + (size_t)b * NSTATE, gc[1], q, tid);
}

// K_layer<L>: entry = own slice + deferred wire-0 gate of layer L-1; 4 local
// passes; exit = wire-1 gate + Rinv relabel scatter.  (r8, verified)
template<int L>
__global__ __launch_bounds__(TPB) void k_layer(
    const float* __restrict__ states, const float* __restrict__ weights,
    const float2* __restrict__ Sin, float2* __restrict__ Sout)
{
    extern __shared__ float2 psi[];
    __shared__ float4 gc[NW];
    __shared__ float4 ge_s;
    const unsigned gid = blockIdx.x, q = gid >> 7, b = gid & 127u;
    const unsigned tid = threadIdx.x;

    if (tid < NW) gc[tid] = fused_coef(weights, states, (int)b, L, (int)tid);
    if (tid == NW) ge_s = fused_coef(weights, states, (int)b, L - 1, 0);
    __syncthreads();
    const float4 ge = ge_s;

    const float2* src = Sin + (size_t)b * NSTATE + (size_t)q * HALF;
#pragma unroll
    for (int m = 0; m < 4; ++m) {
        const unsigned ic = tid + (unsigned)m * TPB;   // bit12 = 0
        const float2 f0 = src[ic];
        const float2 f1 = src[ic ^ 0x1FFFu];
        const unsigned rc = (q ^ ic) & 1u;
        const float aar = ge.x, aai = rc ? -ge.y : ge.y;
        const float bbr = rc ? -ge.z : ge.z, bbi = ge.w;
        float2 oc, op;   // oc = aa*f0 + bb*f1 ; op = conj(aa)*f1 - conj(bb)*f0
        oc.x = aar*f0.x - aai*f0.y + bbr*f1.x - bbi*f1.y;
        oc.y = aar*f0.y + aai*f0.x + bbr*f1.y + bbi*f1.x;
        op.x = aar*f1.x + aai*f1.y - (bbr*f0.x + bbi*f0.y);
        op.y = aar*f1.y - aai*f1.x - (bbr*f0.y - bbi*f0.x);
        psi[ic]           = oc;
        psi[ic ^ 0x1FFFu] = op;
    }
    __syncthreads();

    pass3<0, 1, 7>(psi, gc, tid);  __syncthreads();
    pass3<3, 3, 1>(psi, gc, tid);  __syncthreads();
    pass3<6, 0, 0>(psi, gc, tid);  __syncthreads();
    pass3<9, 0, 0>(psi, gc, tid);  __syncthreads();

    exit_scatter(psi, Sout + (size_t)b * NSTATE, gc[1], q, tid);
}

// K_final: one block per SAMPLE (both halves): deferred layer-3 wire-0 gate
// + <Z> contraction + head; direct out[b] write (no atomics, no memset).
__global__ __launch_bounds__(TPB) void k_final(
    const float* __restrict__ states, const float* __restrict__ weights,
    const float* __restrict__ head_w, const float* __restrict__ head_b,
    const float2* __restrict__ Sin, float* __restrict__ out)
{
    __shared__ float4 ge_s;
    __shared__ float wsum[TPB / 64];
    const unsigned b = blockIdx.x;
    const unsigned tid = threadIdx.x;

    if (tid == 0) ge_s = fused_coef(weights, states, (int)b, NL - 1, 0);
    __syncthreads();
    const float4 ge = ge_s;

    float hw[NW];
#pragma unroll
    for (int i = 0; i < NW; ++i) hw[i] = head_w[i];

    float hwsumv = 0.0f;
#pragma unroll
    for (int i = 0; i < NW; ++i) hwsumv += hw[i];
    float cvt = hwsumv;
#pragma unroll
    for (int p = 0; p < 10; ++p)
        if ((tid >> p) & 1u) cvt -= 2.0f * hw[13 - p];

    float acc = 0.0f;
#pragma unroll
    for (int qm = 0; qm < 8; ++qm) {
        const unsigned q = (unsigned)qm >> 2;         // half index (bit13)
        const unsigned m = (unsigned)qm & 3u;
        const float2* src = Sin + (size_t)b * NSTATE + (size_t)q * HALF;
        const unsigned ic = tid + m * TPB;            // bit12 = 0
        const float2 f0 = src[ic];
        const float2 f1 = src[ic ^ 0x1FFFu];
        const unsigned rc = (q ^ ic) & 1u;
        const float aar = ge.x, aai = rc ? -ge.y : ge.y;
        const float bbr = rc ? -ge.z : ge.z, bbi = ge.w;
        float2 oc, op;
        oc.x = aar*f0.x - aai*f0.y + bbr*f1.x - bbi*f1.y;
        oc.y = aar*f0.y + aai*f0.x + bbr*f1.y + bbi*f1.x;
        op.x = aar*f1.x + aai*f1.y - (bbr*f0.x + bbi*f0.y);
        op.y = aar*f1.y - aai*f1.x - (bbr*f0.y - bbi*f0.x);
        float cv_c = cvt;
        if (q) cv_c -= 2.0f * hw[0];
        if (m & 1) cv_c -= 2.0f * hw[3];
        if (m & 2) cv_c -= 2.0f * hw[2];
        const float s0w = 1.0f - 2.0f * (float)q;
        const float cv_p = 2.0f * hw[0] * s0w - cv_c;  // partner flips w1..13
        acc += (oc.x*oc.x + oc.y*oc.y) * cv_c
             + (op.x*op.x + op.y*op.y) * cv_p;
    }
#pragma unroll
    for (int off = 32; off > 0; off >>= 1)
        acc += __shfl_down(acc, off, 64);
    if ((tid & 63u) == 0) wsum[tid >> 6] = acc;
    __syncthreads();
    if (tid == 0) {
        float tot = 0.0f;
#pragma unroll
        for (int i = 0; i < TPB / 64; ++i) tot += wsum[i];
        out[b] = tot + head_b[0];
    }
}

extern "C" void kernel_launch(void* const* d_in, const int* in_sizes, int n_in,
                              void* d_out, int out_size, void* d_ws, size_t ws_size,
                              hipStream_t stream) {
    const float* states  = (const float*)d_in[0];  // (128, 16384)
    const float* weights = (const float*)d_in[1];  // (4, 14, 2)
    const float* head_w  = (const float*)d_in[2];  // (1, 14)
    const float* head_b  = (const float*)d_in[3];  // (1,)
    float* out = (float*)d_out;                    // (128,)

    float2* SA = (float2*)d_ws;                    // 16 MB
    float2* SB = SA + (size_t)BATCH * NSTATE;      // 16 MB  (ws >= 32 MB)

    k_layer1  <<<2 * BATCH, TPB, SHBYTES, stream>>>(states, weights, SA);
    k_layer<2><<<2 * BATCH, TPB, SHBYTES, stream>>>(states, weights, SA, SB);
    k_layer<3><<<2 * BATCH, TPB, SHBYTES, stream>>>(states, weights, SB, SA);
    k_final   <<<BATCH, TPB, 0, stream>>>(states, weights, head_w, head_b,
                                          SA, out);
}